// Round 1
// baseline (122.679 us; speedup 1.0000x reference)
//
#include <hip/hip_runtime.h>
#include <math.h>

#define LFFT 16384

__device__ __forceinline__ float2 cadd(float2 a, float2 b){ return make_float2(a.x+b.x, a.y+b.y); }
__device__ __forceinline__ float2 csub(float2 a, float2 b){ return make_float2(a.x-b.x, a.y-b.y); }
__device__ __forceinline__ float2 cmul(float2 a, float2 b){ return make_float2(a.x*b.x - a.y*b.y, a.x*b.y + a.y*b.x); }
// a * conj(b)
__device__ __forceinline__ float2 cmulc(float2 a, float2 b){ return make_float2(a.x*b.x + a.y*b.y, a.y*b.x - a.x*b.y); }

// ---------------------------------------------------------------------------
// Kernel 1: evaluate the S4 generating function K[k] at the L roots of unity
// (double precision for stability near k = L/2 where 1+Omega ~ 1e-16), and
// emit the fp32 twiddle table W[k] = exp(-2*pi*i*k/L).
// ---------------------------------------------------------------------------
__global__ void s4_freq(const float* __restrict__ Lr, const float* __restrict__ Li,
                        const float* __restrict__ Pr, const float* __restrict__ Pi,
                        const float* __restrict__ Br, const float* __restrict__ Bi,
                        const float* __restrict__ Cr, const float* __restrict__ Ci,
                        const float* __restrict__ step_ptr,
                        float2* __restrict__ Kraw, float2* __restrict__ twid)
{
    int k = blockIdx.x * blockDim.x + threadIdx.x;
    if (k >= LFFT) return;
    double theta = (-2.0 * M_PI / (double)LFFT) * (double)k;
    double si, co;
    sincos(theta, &si, &co);
    twid[k] = make_float2((float)co, (float)si);

    double step = (double)step_ptr[0];
    // Omega = co + i si
    double opr = 1.0 + co, opi = si;   // 1 + Omega
    double omr = 1.0 - co, omi = -si;  // 1 - Omega
    double iden = 1.0 / (opr*opr + opi*opi);
    double gs = 2.0 / step;
    double gr = gs * (omr*opr + omi*opi) * iden;   // g = (2/step)(1-Om)/(1+Om)
    double gi = gs * (omi*opr - omr*opi) * iden;
    double cr = 2.0 * opr * iden;                  // c = 2/(1+Om)
    double ci = -2.0 * opi * iden;

    double k00r=0,k00i=0,k01r=0,k01i=0,k10r=0,k10i=0,k11r=0,k11i=0;
    for (int n = 0; n < 64; ++n) {
        double dr = gr - (double)Lr[n];
        double di = gi - (double)Li[n];
        double id2 = 1.0 / (dr*dr + di*di);
        double vr =  dr * id2;       // inv = 1/(g - Lambda)
        double vi = -di * id2;
        double a0r = (double)Cr[n], a0i = -(double)Ci[n];  // conj(C)
        double a1r = (double)Pr[n], a1i = -(double)Pi[n];  // conj(P)
        double br  = (double)Br[n], bi  = (double)Bi[n];
        double pr  = (double)Pr[n], pi  = (double)Pi[n];
        double e00r = a0r*br - a0i*bi, e00i = a0r*bi + a0i*br;   // conj(C)*B
        double e01r = a0r*pr - a0i*pi, e01i = a0r*pi + a0i*pr;   // conj(C)*P
        double e10r = a1r*br - a1i*bi, e10i = a1r*bi + a1i*br;   // conj(P)*B
        double e11r = a1r*pr - a1i*pi, e11i = a1r*pi + a1i*pr;   // conj(P)*P
        k00r += vr*e00r - vi*e00i;  k00i += vr*e00i + vi*e00r;
        k01r += vr*e01r - vi*e01i;  k01i += vr*e01i + vi*e01r;
        k10r += vr*e10r - vi*e10i;  k10i += vr*e10i + vi*e10r;
        k11r += vr*e11r - vi*e11i;  k11i += vr*e11i + vi*e11r;
    }
    // K = c * (k00 - k01 * (1/(1+k11)) * k10)
    double rr = 1.0 + k11r, ri = k11i;
    double ir2 = 1.0 / (rr*rr + ri*ri);
    double qr0 = k01r*k10r - k01i*k10i;
    double qi0 = k01r*k10i + k01i*k10r;
    double qr = (qr0*rr + qi0*ri) * ir2;
    double qi = (qi0*rr - qr0*ri) * ir2;
    double sr = k00r - qr, sim = k00i - qi;
    double Krr = cr*sr - ci*sim;
    double Kri = cr*sim + ci*sr;
    Kraw[k] = make_float2((float)Krr, (float)Kri);
}

// ---------------------------------------------------------------------------
// Kernel 2: Hermitian-symmetrize K (so Re(IFFT(K*X)) == IFFT(Ktilde*X) for
// real input rows), fold in 1/L, and store in base-4 digit-reversed order so
// the spectral multiply happens directly in the DIF output ordering.
// ---------------------------------------------------------------------------
__global__ void build_kperm(const float2* __restrict__ Kraw, float2* __restrict__ Kperm)
{
    int p = blockIdx.x * blockDim.x + threadIdx.x;
    if (p >= LFFT) return;
    unsigned r = 0, t = (unsigned)p;
    #pragma unroll
    for (int i = 0; i < 7; ++i) { r = (r << 2) | (t & 3u); t >>= 2; }
    float2 a = Kraw[r];
    float2 b = Kraw[(LFFT - r) & (LFFT - 1)];
    const float s = 0.5f / (float)LFFT;
    Kperm[p] = make_float2(s * (a.x + b.x), s * (a.y - b.y));
}

// ---------------------------------------------------------------------------
// Kernel 3: per block, pack TWO real rows as z = x0 + i*x1, run a 16384-pt
// radix-4 DIF FFT in LDS (natural -> digit-reversed), multiply by the
// digit-reversed Hermitian kernel, run radix-4 DIT inverse
// (digit-reversed -> natural), write Re -> row0, Im -> row1.
// ---------------------------------------------------------------------------
__global__ __launch_bounds__(512) void fft_conv(
    const float* __restrict__ x, float* __restrict__ y,
    const float2* __restrict__ twid, const float2* __restrict__ kperm)
{
    __shared__ float2 z[LFFT];   // 128 KiB
    const int tid = threadIdx.x;
    const size_t rowbase = (size_t)blockIdx.x * 2u * LFFT;
    const float4* x0 = (const float4*)(x + rowbase);
    const float4* x1 = x0 + LFFT / 4;

    for (int i = tid; i < LFFT / 4; i += 512) {
        float4 a = x0[i];
        float4 b = x1[i];
        z[4*i+0] = make_float2(a.x, b.x);
        z[4*i+1] = make_float2(a.y, b.y);
        z[4*i+2] = make_float2(a.z, b.z);
        z[4*i+3] = make_float2(a.w, b.w);
    }
    __syncthreads();

    // ---- forward: radix-4 DIF, stages s = 6..0 (Ns = 4^(s+1)) ----
    for (int s = 6; s >= 0; --s) {
        const int q   = 1 << (2*s);
        const int tsh = 12 - 2*s;     // twiddle stride shift: L/Ns = 1<<tsh
        for (int id = tid; id < LFFT / 4; id += 512) {
            const int n1 = id & (q - 1);
            const int i0 = ((id >> (2*s)) << (2*s + 2)) + n1;
            float2 a0 = z[i0];
            float2 a1 = z[i0 + q];
            float2 a2 = z[i0 + 2*q];
            float2 a3 = z[i0 + 3*q];
            float2 t0 = cadd(a0, a2);
            float2 t1 = csub(a0, a2);
            float2 t2 = cadd(a1, a3);
            float2 t3 = csub(a1, a3);
            float2 y0 = cadd(t0, t2);
            float2 u2 = csub(t0, t2);
            float2 u1 = make_float2(t1.x + t3.y, t1.y - t3.x);  // t1 - i*t3
            float2 u3 = make_float2(t1.x - t3.y, t1.y + t3.x);  // t1 + i*t3
            const int tb = n1 << tsh;
            float2 w1 = twid[tb];
            float2 w2 = twid[2*tb];
            float2 w3 = twid[3*tb];
            z[i0]       = y0;
            z[i0 + q]   = cmul(u1, w1);
            z[i0 + 2*q] = cmul(u2, w2);
            z[i0 + 3*q] = cmul(u3, w3);
        }
        __syncthreads();
    }

    // ---- pointwise multiply in digit-reversed frequency domain ----
    for (int p = tid; p < LFFT; p += 512) {
        z[p] = cmul(z[p], kperm[p]);
    }
    __syncthreads();

    // ---- inverse: radix-4 DIT, stages s = 0..6 ----
    for (int s = 0; s <= 6; ++s) {
        const int q   = 1 << (2*s);
        const int tsh = 12 - 2*s;
        for (int id = tid; id < LFFT / 4; id += 512) {
            const int n1 = id & (q - 1);
            const int i0 = ((id >> (2*s)) << (2*s + 2)) + n1;
            const int tb = n1 << tsh;
            float2 w1 = twid[tb];
            float2 w2 = twid[2*tb];
            float2 w3 = twid[3*tb];
            float2 b0 = z[i0];
            float2 b1 = cmulc(z[i0 + q],   w1);   // conj twiddles
            float2 b2 = cmulc(z[i0 + 2*q], w2);
            float2 b3 = cmulc(z[i0 + 3*q], w3);
            float2 t0 = cadd(b0, b2);
            float2 t1 = csub(b0, b2);
            float2 t2 = cadd(b1, b3);
            float2 t3 = csub(b1, b3);
            float2 c0 = cadd(t0, t2);
            float2 c2 = csub(t0, t2);
            float2 c1 = make_float2(t1.x - t3.y, t1.y + t3.x);  // t1 + i*t3
            float2 c3 = make_float2(t1.x + t3.y, t1.y - t3.x);  // t1 - i*t3
            z[i0]       = c0;
            z[i0 + q]   = c1;
            z[i0 + 2*q] = c2;
            z[i0 + 3*q] = c3;
        }
        __syncthreads();
    }

    // ---- unpack: Re -> row0, Im -> row1 ----
    float4* o0 = (float4*)(y + rowbase);
    float4* o1 = o0 + LFFT / 4;
    for (int i = tid; i < LFFT / 4; i += 512) {
        float2 z0 = z[4*i+0];
        float2 z1 = z[4*i+1];
        float2 z2 = z[4*i+2];
        float2 z3 = z[4*i+3];
        o0[i] = make_float4(z0.x, z1.x, z2.x, z3.x);
        o1[i] = make_float4(z0.y, z1.y, z2.y, z3.y);
    }
}

extern "C" void kernel_launch(void* const* d_in, const int* in_sizes, int n_in,
                              void* d_out, int out_size, void* d_ws, size_t ws_size,
                              hipStream_t stream)
{
    const float* x  = (const float*)d_in[0];
    const float* Lr = (const float*)d_in[1];
    const float* Li = (const float*)d_in[2];
    const float* Pr = (const float*)d_in[3];
    const float* Pi = (const float*)d_in[4];
    const float* Br = (const float*)d_in[5];
    const float* Bi = (const float*)d_in[6];
    const float* Cr = (const float*)d_in[7];
    const float* Ci = (const float*)d_in[8];
    const float* st = (const float*)d_in[9];

    const int rows = in_sizes[0] / LFFT;   // 1024

    float2* twid  = (float2*)d_ws;          // LFFT float2
    float2* Kraw  = twid + LFFT;            // LFFT float2
    float2* Kperm = Kraw + LFFT;            // LFFT float2  (total 384 KiB)

    s4_freq<<<LFFT / 256, 256, 0, stream>>>(Lr, Li, Pr, Pi, Br, Bi, Cr, Ci, st,
                                            Kraw, twid);
    build_kperm<<<LFFT / 256, 256, 0, stream>>>(Kraw, Kperm);
    fft_conv<<<rows / 2, 512, 0, stream>>>(x, (float*)d_out, twid, Kperm);
}

// Round 2
// 88.562 us; speedup vs baseline: 1.3852x; 1.3852x over previous
//
#include <hip/hip_runtime.h>
#include <math.h>

#define LFFT 16384
#define NTHREADS 1024
#define LDS_PITCH 17   // float2 per row (16 + 1 pad)

__device__ __forceinline__ float2 cadd(float2 a, float2 b){ return make_float2(a.x+b.x, a.y+b.y); }
__device__ __forceinline__ float2 csub(float2 a, float2 b){ return make_float2(a.x-b.x, a.y-b.y); }
__device__ __forceinline__ float2 cmul(float2 a, float2 b){ return make_float2(a.x*b.x - a.y*b.y, a.x*b.y + a.y*b.x); }

// a * (i*S)   (S = +1 or -1, compile-time)
template<int S> __device__ __forceinline__ float2 mul_is(float2 a) {
    return make_float2(-(float)S * a.y, (float)S * a.x);
}

// ---------------------------------------------------------------------------
// Radix-4 butterfly. S = -1: forward DFT-4 (natural order out).
//                    S = +1: inverse (unnormalized).
// a1_out = t1 + S*i*t3 ; a3_out = t1 - S*i*t3
// ---------------------------------------------------------------------------
template<int S> __device__ __forceinline__ void dft4_t(float2& a0, float2& a1, float2& a2, float2& a3) {
    float2 t0 = cadd(a0, a2);
    float2 t1 = csub(a0, a2);
    float2 t2 = cadd(a1, a3);
    float2 t3 = csub(a1, a3);
    a0 = cadd(t0, t2);
    a2 = csub(t0, t2);
    const float s = (float)S;
    a1 = make_float2(t1.x - s * t3.y, t1.y + s * t3.x);
    a3 = make_float2(t1.x + s * t3.y, t1.y - s * t3.x);
}

#define C16A 0.92387953251128675613f  // cos(pi/8)
#define C16B 0.70710678118654752440f  // sqrt(2)/2
#define C16C 0.38268343236508977173f  // sin(pi/8)

// ---------------------------------------------------------------------------
// Fully-unrolled 16-point DFT, natural order in AND out (r[n] -> r[k]).
// Four-step: 16 = 4(a, stride 4) x 4(b, stride 1):
//   F[b][ka] = DFT4_a(r[b + 4a]);  F[b][ka] *= W16^(b*ka);
//   r[ka + 4kb] = DFT4_b(F[.][ka])[kb]
// S = -1 forward, +1 inverse(unnormalized, conj twiddles).
// ---------------------------------------------------------------------------
template<int S> __device__ __forceinline__ void dft16_t(float2 r[16]) {
    const float s = (float)S;
    const float2 w1 = make_float2( C16A, s * C16C);
    const float2 w2 = make_float2( C16B, s * C16B);
    const float2 w3 = make_float2( C16C, s * C16A);
    const float2 w6 = make_float2(-C16B, s * C16B);
    const float2 w9 = make_float2(-C16A, -s * C16C);
    float2 g[4][4];
    #pragma unroll
    for (int b = 0; b < 4; ++b) {
        float2 a0 = r[b], a1 = r[b+4], a2 = r[b+8], a3 = r[b+12];
        dft4_t<S>(a0, a1, a2, a3);
        g[b][0] = a0; g[b][1] = a1; g[b][2] = a2; g[b][3] = a3;
    }
    g[1][1] = cmul(g[1][1], w1);  g[1][2] = cmul(g[1][2], w2);  g[1][3] = cmul(g[1][3], w3);
    g[2][1] = cmul(g[2][1], w2);  g[2][2] = mul_is<S>(g[2][2]); g[2][3] = cmul(g[2][3], w6);
    g[3][1] = cmul(g[3][1], w3);  g[3][2] = cmul(g[3][2], w6);  g[3][3] = cmul(g[3][3], w9);
    #pragma unroll
    for (int ka = 0; ka < 4; ++ka) {
        float2 a0 = g[0][ka], a1 = g[1][ka], a2 = g[2][ka], a3 = g[3][ka];
        dft4_t<S>(a0, a1, a2, a3);
        r[ka] = a0; r[ka+4] = a1; r[ka+8] = a2; r[ka+12] = a3;
    }
}

// r[k] *= w^k, k = 1..15 (two parallel chains for latency)
__device__ __forceinline__ void twiddle15(float2 r[16], float2 w) {
    float2 w2 = cmul(w, w);
    float2 we = w2;            // w^2
    float2 wo = cmul(w, w2);   // w^3
    r[1] = cmul(r[1], w);
    r[2] = cmul(r[2], we);
    r[3] = cmul(r[3], wo);
    #pragma unroll
    for (int j = 2; j <= 7; ++j) {
        we = cmul(we, w2);  r[2*j]   = cmul(r[2*j],   we);
        wo = cmul(wo, w2);  r[2*j+1] = cmul(r[2*j+1], wo);
    }
}

// ---------------------------------------------------------------------------
// Kernel 1: S4 generating function K[k] at L roots of unity (fp64 for the
// near-pole at k=L/2) + fp32 twiddle table W[k] = exp(-2 pi i k / L).
// ---------------------------------------------------------------------------
__global__ void s4_freq(const float* __restrict__ Lr, const float* __restrict__ Li,
                        const float* __restrict__ Pr, const float* __restrict__ Pi,
                        const float* __restrict__ Br, const float* __restrict__ Bi,
                        const float* __restrict__ Cr, const float* __restrict__ Ci,
                        const float* __restrict__ step_ptr,
                        float2* __restrict__ Kraw, float2* __restrict__ twid)
{
    int k = blockIdx.x * blockDim.x + threadIdx.x;
    if (k >= LFFT) return;
    double theta = (-2.0 * M_PI / (double)LFFT) * (double)k;
    double si, co;
    sincos(theta, &si, &co);
    twid[k] = make_float2((float)co, (float)si);

    double step = (double)step_ptr[0];
    double opr = 1.0 + co, opi = si;   // 1 + Omega
    double omr = 1.0 - co, omi = -si;  // 1 - Omega
    double iden = 1.0 / (opr*opr + opi*opi);
    double gs = 2.0 / step;
    double gr = gs * (omr*opr + omi*opi) * iden;
    double gi = gs * (omi*opr - omr*opi) * iden;
    double cr = 2.0 * opr * iden;
    double ci = -2.0 * opi * iden;

    double k00r=0,k00i=0,k01r=0,k01i=0,k10r=0,k10i=0,k11r=0,k11i=0;
    for (int n = 0; n < 64; ++n) {
        double dr = gr - (double)Lr[n];
        double di = gi - (double)Li[n];
        double id2 = 1.0 / (dr*dr + di*di);
        double vr =  dr * id2;
        double vi = -di * id2;
        double a0r = (double)Cr[n], a0i = -(double)Ci[n];
        double a1r = (double)Pr[n], a1i = -(double)Pi[n];
        double br  = (double)Br[n], bi  = (double)Bi[n];
        double pr  = (double)Pr[n], pi  = (double)Pi[n];
        double e00r = a0r*br - a0i*bi, e00i = a0r*bi + a0i*br;
        double e01r = a0r*pr - a0i*pi, e01i = a0r*pi + a0i*pr;
        double e10r = a1r*br - a1i*bi, e10i = a1r*bi + a1i*br;
        double e11r = a1r*pr - a1i*pi, e11i = a1r*pi + a1i*pr;
        k00r += vr*e00r - vi*e00i;  k00i += vr*e00i + vi*e00r;
        k01r += vr*e01r - vi*e01i;  k01i += vr*e01i + vi*e01r;
        k10r += vr*e10r - vi*e10i;  k10i += vr*e10i + vi*e10r;
        k11r += vr*e11r - vi*e11i;  k11i += vr*e11i + vi*e11r;
    }
    double rr = 1.0 + k11r, ri = k11i;
    double ir2 = 1.0 / (rr*rr + ri*ri);
    double qr0 = k01r*k10r - k01i*k10i;
    double qi0 = k01r*k10i + k01i*k10r;
    double qr = (qr0*rr + qi0*ri) * ir2;
    double qi = (qi0*rr - qr0*ri) * ir2;
    double sr = k00r - qr, sim = k00i - qi;
    double Krr = cr*sr - ci*sim;
    double Kri = cr*sim + ci*sr;
    Kraw[k] = make_float2((float)Krr, (float)Kri);
}

// ---------------------------------------------------------------------------
// Kernel 2: Hermitian-symmetrize K, fold in 0.5/L, and store in the exact
// (thread t, register slot j) order of the fft_conv multiply point:
//   m = k1 + 16*k3 + 256*(4*k5h + k5l) + 4096*k6
//   k1=t>>6, k3=(t>>2)&15, k5h=t&3, k5l=j>>2, k6=j&3,  p = t*16 + j
// ---------------------------------------------------------------------------
__global__ void build_kperm(const float2* __restrict__ Kraw, float2* __restrict__ Kperm)
{
    int p = blockIdx.x * blockDim.x + threadIdx.x;
    if (p >= LFFT) return;
    int t = p >> 4, j = p & 15;
    int k1 = t >> 6, k3 = (t >> 2) & 15, k5h = t & 3;
    int k5l = j >> 2, k6 = j & 3;
    int m = k1 + 16*k3 + 256*(4*k5h + k5l) + 4096*k6;
    float2 a = Kraw[m];
    float2 b = Kraw[(LFFT - m) & (LFFT - 1)];
    const float s = 0.5f / (float)LFFT;
    Kperm[p] = make_float2(s * (a.x + b.x), s * (a.y - b.y));
}

// ---------------------------------------------------------------------------
// Kernel 3: register-resident four-step FFT/IFFT, 16384 = 16 x 16 x 16 x 4.
// 1024 threads x 16 float2 in registers; LDS only for 6 transposes
// (stride-17 padded rows; writer scatters, reader reads own row; all
// patterns verified 4-lanes-per-bank-pair = conflict-free optimum).
// Two real rows packed as z = x0 + i*x1; Hermitian kernel keeps the
// product spectrum Hermitian-compatible so output is y0 + i*y1 directly.
// ---------------------------------------------------------------------------
__global__ __launch_bounds__(NTHREADS, 4) void fft_conv(
    const float* __restrict__ x, float* __restrict__ y,
    const float2* __restrict__ twid, const float2* __restrict__ kperm)
{
    __shared__ float2 lds[NTHREADS * LDS_PITCH];   // 1024 rows x 17 -> 136 KiB
    const int t = threadIdx.x;
    const size_t rowbase = (size_t)blockIdx.x * 2u * LFFT;
    const float* x0 = x + rowbase;
    const float* x1 = x0 + LFFT;

    float2 r[16];

    // ---- load: thread t owns n = t + 1024*a (coalesced) ----
    #pragma unroll
    for (int a = 0; a < 16; ++a)
        r[a] = make_float2(x0[t + NTHREADS*a], x1[t + NTHREADS*a]);

    // ---- P1: DFT-16 over a, twiddle W_16384^(t*k1) ----
    dft16_t<-1>(r);
    twiddle15(r, twid[t]);

    // ---- T1: send r[k1] -> row 64*k1 + (t&63), col t>>6 ----
    #pragma unroll
    for (int k = 0; k < 16; ++k)
        lds[(k*64 + (t & 63)) * LDS_PITCH + (t >> 6)] = r[k];
    __syncthreads();
    #pragma unroll
    for (int a = 0; a < 16; ++a)
        r[a] = lds[t * LDS_PITCH + a];
    __syncthreads();

    // ---- P2: DFT-16 over a2, twiddle W_1024^((t&63)*k3) ----
    dft16_t<-1>(r);
    twiddle15(r, twid[16 * (t & 63)]);

    // ---- T2: send r[k3] -> row 64*(t>>6) + 4*k3 + (t&3), col (t>>2)&15 ----
    #pragma unroll
    for (int k = 0; k < 16; ++k)
        lds[((t >> 6)*64 + k*4 + (t & 3)) * LDS_PITCH + ((t >> 2) & 15)] = r[k];
    __syncthreads();
    #pragma unroll
    for (int a = 0; a < 16; ++a)
        r[a] = lds[t * LDS_PITCH + a];
    __syncthreads();

    // ---- P3: DFT-16 over a3, twiddle W_64^((t&3)*k5) ----
    dft16_t<-1>(r);
    twiddle15(r, twid[256 * (t & 3)]);

    // ---- T3: send r[k5] -> row (t&~3) + (k5>>2), col 4*(k5&3) + (t&3) ----
    #pragma unroll
    for (int k = 0; k < 16; ++k)
        lds[((t & ~3) + (k >> 2)) * LDS_PITCH + 4*(k & 3) + (t & 3)] = r[k];
    __syncthreads();
    #pragma unroll
    for (int j = 0; j < 16; ++j)
        r[j] = lds[t * LDS_PITCH + j];          // r[4*k5l + b3]
    __syncthreads();

    // ---- P4: DFT-4 over b3 within each k5l group -> Z in registers ----
    #pragma unroll
    for (int q = 0; q < 4; ++q)
        dft4_t<-1>(r[4*q], r[4*q+1], r[4*q+2], r[4*q+3]);

    // ---- pointwise multiply by pre-permuted Hermitian kernel ----
    {
        const float4* kp4 = (const float4*)(kperm + t * 16);
        float4 kv[8];
        #pragma unroll
        for (int i = 0; i < 8; ++i) kv[i] = kp4[i];
        #pragma unroll
        for (int i = 0; i < 8; ++i) {
            r[2*i]   = cmul(r[2*i],   make_float2(kv[i].x, kv[i].y));
            r[2*i+1] = cmul(r[2*i+1], make_float2(kv[i].z, kv[i].w));
        }
    }

    // ---- IP4: inverse DFT-4 over k6 ----
    #pragma unroll
    for (int q = 0; q < 4; ++q)
        dft4_t<1>(r[4*q], r[4*q+1], r[4*q+2], r[4*q+3]);

    // ---- IT3: send r[4*k5l + b3] -> row (t&~3)+b3, col (4*(t&3)+k5l)^k3 ----
    #pragma unroll
    for (int j = 0; j < 16; ++j)
        lds[((t & ~3) + (j & 3)) * LDS_PITCH + ((4*(t & 3) + (j >> 2)) ^ ((t >> 2) & 15))] = r[j];
    __syncthreads();
    #pragma unroll
    for (int k = 0; k < 16; ++k)
        r[k] = lds[t * LDS_PITCH + (k ^ ((t >> 2) & 15))];
    __syncthreads();

    // ---- IP3: conj twiddle W_64, inverse DFT-16 over k5 -> a3 ----
    {
        float2 w = twid[256 * (t & 3)];
        twiddle15(r, make_float2(w.x, -w.y));
    }
    dft16_t<1>(r);

    // ---- IT2: send r[a3] -> row 64*(t>>6) + (t&3) + 4*a3, col (t>>2)&15 ----
    #pragma unroll
    for (int a = 0; a < 16; ++a)
        lds[((t >> 6)*64 + (t & 3) + 4*a) * LDS_PITCH + ((t >> 2) & 15)] = r[a];
    __syncthreads();
    #pragma unroll
    for (int k = 0; k < 16; ++k)
        r[k] = lds[t * LDS_PITCH + k];
    __syncthreads();

    // ---- IP2: conj twiddle W_1024, inverse DFT-16 over k3 -> a2 ----
    {
        float2 w = twid[16 * (t & 63)];
        twiddle15(r, make_float2(w.x, -w.y));
    }
    dft16_t<1>(r);

    // ---- IT1: send r[a2] -> row (t&63) + 64*a2, col t>>6 ----
    #pragma unroll
    for (int a = 0; a < 16; ++a)
        lds[((t & 63) + 64*a) * LDS_PITCH + (t >> 6)] = r[a];
    __syncthreads();
    #pragma unroll
    for (int k = 0; k < 16; ++k)
        r[k] = lds[t * LDS_PITCH + k];

    // ---- IP1: conj twiddle W_16384, inverse DFT-16 over k1 -> a ----
    {
        float2 w = twid[t];
        twiddle15(r, make_float2(w.x, -w.y));
    }
    dft16_t<1>(r);

    // ---- store: Re -> row0, Im -> row1 (coalesced) ----
    float* y0 = y + rowbase;
    float* y1 = y0 + LFFT;
    #pragma unroll
    for (int a = 0; a < 16; ++a) {
        y0[t + NTHREADS*a] = r[a].x;
        y1[t + NTHREADS*a] = r[a].y;
    }
}

extern "C" void kernel_launch(void* const* d_in, const int* in_sizes, int n_in,
                              void* d_out, int out_size, void* d_ws, size_t ws_size,
                              hipStream_t stream)
{
    const float* x  = (const float*)d_in[0];
    const float* Lr = (const float*)d_in[1];
    const float* Li = (const float*)d_in[2];
    const float* Pr = (const float*)d_in[3];
    const float* Pi = (const float*)d_in[4];
    const float* Br = (const float*)d_in[5];
    const float* Bi = (const float*)d_in[6];
    const float* Cr = (const float*)d_in[7];
    const float* Ci = (const float*)d_in[8];
    const float* st = (const float*)d_in[9];

    const int rows = in_sizes[0] / LFFT;   // 1024

    float2* twid  = (float2*)d_ws;          // LFFT float2
    float2* Kraw  = twid + LFFT;            // LFFT float2
    float2* Kperm = Kraw + LFFT;            // LFFT float2

    s4_freq<<<LFFT / 256, 256, 0, stream>>>(Lr, Li, Pr, Pi, Br, Bi, Cr, Ci, st,
                                            Kraw, twid);
    build_kperm<<<LFFT / 256, 256, 0, stream>>>(Kraw, Kperm);
    fft_conv<<<rows / 2, NTHREADS, 0, stream>>>(x, (float*)d_out, twid, Kperm);
}